// Round 5
// baseline (99.308 us; speedup 1.0000x reference)
//
#include <hip/hip_runtime.h>
#include <math.h>

// Problem constants (B=2, D=512, K=32, H=W=64 -> N=4096)
#define B_DIM 2
#define D_DIM 512
#define K_DIM 32
#define N_DIM 4096

typedef float v2f __attribute__((ext_vector_type(2)));

// packed fp32 FMA, broadcasting src1's LO half to both lanes: d += a * b.lo
__device__ __forceinline__ void pk_bl(v2f& d, v2f a, v2f b) {
    asm("v_pk_fma_f32 %0, %1, %2, %0 op_sel:[0,0,0] op_sel_hi:[1,0,1]"
        : "+v"(d) : "v"(a), "v"(b));
}
// broadcast src1's HI half: d += a * b.hi
__device__ __forceinline__ void pk_bh(v2f& d, v2f a, v2f b) {
    asm("v_pk_fma_f32 %0, %1, %2, %0 op_sel:[0,1,0] op_sel_hi:[1,1,1]"
        : "+v"(d) : "v"(a), "v"(b));
}

// ---------------------------------------------------------------------------
// K1: distances + softmax Q. Also zeroes nsq + counter (consumed later).
// dist[b,n,k] = sum_d A*x^2 + B2*x + A*c^2,  A = s^2, B2 = -2 s^2 c
// grid = 512 = B * 256 n-tiles of 16; block = 256 threads (4 waves)
// Thread (dp=tid&63, kp=tid>>6) owns d-slice {4dp..4dp+3, 256+4dp..+3} and
// k-slice [8kp,8kp+8). A/B2 in registers (v2f k-pairs); x streamed from LDS
// (conflict-free b128). Hot loop uses v_pk_fma_f32 with op_sel x-broadcast:
// 64 pk + 8 mul per n vs 128 scalar FMA. d-sum: shfl butterfly 64->16 + LDS.
// ---------------------------------------------------------------------------
__global__ __launch_bounds__(256, 2)
void k_dist_q(const float* __restrict__ X, const float* __restrict__ CW,
              const float* __restrict__ SC, float* __restrict__ Qout,
              float* __restrict__ nsq, int* __restrict__ cnt)
{
    __shared__ __align__(16) float xlds[16 * 516];     // [n 16][d 512, stride 516]
    __shared__ __align__(16) float red[16 * 16 * 36];  // [n 16][i 16][k 32 +4]

    const int tid = threadIdx.x;
    const int b  = blockIdx.x >> 8;
    const int n0 = (blockIdx.x & 255) << 4;   // 16 n per block
    const int dp = tid & 63;
    const int kp = tid >> 6;
    const int k0 = kp << 3;

    if (blockIdx.x == 0) {
        if (tid < 64) nsq[tid] = 0.f;
        if (tid == 64) *cnt = 0;
    }

    // ---- stage 16 n x 512 d (transposed to [n][d]); 64-B coalesced reads ----
    const float* xsrc = X + (size_t)b * D_DIM * N_DIM + n0;
#pragma unroll
    for (int j = 0; j < 8; ++j) {
        const int d  = (tid >> 2) + (j << 6);
        const int n4 = (tid & 3) << 2;
        float4 v = *(const float4*)(xsrc + (size_t)d * N_DIM + n4);
        xlds[(n4 + 0) * 516 + d] = v.x;
        xlds[(n4 + 1) * 516 + d] = v.y;
        xlds[(n4 + 2) * 516 + d] = v.z;
        xlds[(n4 + 3) * 516 + d] = v.w;
    }

    // ---- prologue: register tables (overlaps other waves' staging) ----
    float cv[8][8];                    // cv[kk][dd] = codeword value
#pragma unroll
    for (int kk = 0; kk < 8; ++kk) {
        const float* cr = CW + (k0 + kk) * D_DIM + (dp << 2);
        float4 c0 = *(const float4*)(cr);
        float4 c1 = *(const float4*)(cr + 256);
        cv[kk][0] = c0.x; cv[kk][1] = c0.y; cv[kk][2] = c0.z; cv[kk][3] = c0.w;
        cv[kk][4] = c1.x; cv[kk][5] = c1.y; cv[kk][6] = c1.z; cv[kk][7] = c1.w;
    }
    v2f A2[8][4], B2r[8][4], ckp2[4];  // k-pairs: [dd][kk2], k = k0 + 2*kk2 + lane
#pragma unroll
    for (int kk2 = 0; kk2 < 4; ++kk2) ckp2[kk2] = (v2f)(0.f);
#pragma unroll
    for (int dd = 0; dd < 8; ++dd) {
        const int d = (dd < 4) ? ((dp << 2) + dd) : (256 + (dp << 2) + (dd - 4));
        float4 s0 = *(const float4*)(SC + d * K_DIM + k0);
        float4 s1 = *(const float4*)(SC + d * K_DIM + k0 + 4);
        float sv[8] = {s0.x, s0.y, s0.z, s0.w, s1.x, s1.y, s1.z, s1.w};
#pragma unroll
        for (int kk2 = 0; kk2 < 4; ++kk2) {
#pragma unroll
            for (int h = 0; h < 2; ++h) {
                const int kk = 2 * kk2 + h;
                float c = cv[kk][dd];
                float a = sv[kk] * sv[kk];
                A2[dd][kk2][h]  = a;
                B2r[dd][kk2][h] = -2.f * a * c;
                ckp2[kk2][h] = fmaf(a * c, c, ckp2[kk2][h]);
            }
        }
    }
    __syncthreads();

    // ---- main: 16 n, packed FMAs ----
#pragma unroll
    for (int n = 0; n < 16; ++n) {
        v2f d2[4];
#pragma unroll
        for (int kk2 = 0; kk2 < 4; ++kk2) d2[kk2] = ckp2[kk2];
        float4 xa = *(const float4*)(&xlds[n * 516 + (dp << 2)]);
        float4 xb = *(const float4*)(&xlds[n * 516 + (dp << 2) + 256]);
        v2f xp[4] = {{xa.x, xa.y}, {xa.z, xa.w}, {xb.x, xb.y}, {xb.z, xb.w}};
#pragma unroll
        for (int dq = 0; dq < 4; ++dq) {
            v2f x2p = xp[dq] * xp[dq];
#pragma unroll
            for (int kk2 = 0; kk2 < 4; ++kk2) {
                pk_bl(d2[kk2], A2[2 * dq][kk2],      x2p);
                pk_bl(d2[kk2], B2r[2 * dq][kk2],     xp[dq]);
                pk_bh(d2[kk2], A2[2 * dq + 1][kk2],  x2p);
                pk_bh(d2[kk2], B2r[2 * dq + 1][kk2], xp[dq]);
            }
        }
        float dist[8] = {d2[0].x, d2[0].y, d2[1].x, d2[1].y,
                         d2[2].x, d2[2].y, d2[3].x, d2[3].y};
#pragma unroll
        for (int kk = 0; kk < 8; ++kk) {
            dist[kk] += __shfl_xor(dist[kk], 32);
            dist[kk] += __shfl_xor(dist[kk], 16);
        }
        if (dp < 16) {
            float* r = &red[(n * 16 + dp) * 36 + k0];
            *(float4*)(r)     = make_float4(dist[0], dist[1], dist[2], dist[3]);
            *(float4*)(r + 4) = make_float4(dist[4], dist[5], dist[6], dist[7]);
        }
    }
    __syncthreads();

    // ---- reduce 16 partials + softmax over k (32-lane groups), 2 passes ----
#pragma unroll
    for (int h = 0; h < 2; ++h) {
        const int n = (tid >> 5) + (h << 3);
        const int k = tid & 31;
        float dsum = 0.f;
#pragma unroll
        for (int i = 0; i < 16; ++i) dsum += red[(n * 16 + i) * 36 + k];
        float m = dsum;
#pragma unroll
        for (int mk = 16; mk >= 1; mk >>= 1)
            m = fminf(m, __shfl_xor(m, mk));
        float e = __expf(-0.5f * (dsum - m));
        float ssum = e;
#pragma unroll
        for (int mk = 16; mk >= 1; mk >>= 1)
            ssum += __shfl_xor(ssum, mk);
        Qout[((size_t)b * N_DIM + n0 + n) * K_DIM + k] = __fdividef(e, ssum);
    }
}

// ---------------------------------------------------------------------------
// K2: T partials + per-slab Q mass. T[b,d,k] = sum_n Q[b,n,k] * X[b,d,n],
// n split 32 ways. grid = 512 = b(2) x dtile(8 of 64 d) x ns(32 of 128 n).
// Thread (dp=tid&7, kp=(tid>>3)&3, nsub=tid>>5): 8d x 8k tile, k CONTIGUOUS
// (k0t=8kp) so Qs in [n][k] layout yields j-paired float4 loads feeding
// v_pk_fma_f32 with op_sel x-broadcast (128 pk vs 256 scalar per s-iter).
// dt==0 blocks also write Mpart[ns,b,k] = sum_{128 n} Q (no atomics).
// ---------------------------------------------------------------------------
__global__ __launch_bounds__(256, 2)
void k_tpart(const float* __restrict__ X, const float* __restrict__ Qin,
             float* __restrict__ TP, float* __restrict__ Mpart)
{
    __shared__ __align__(16) float Xs[64 * 68];        // [d 64][n 64 +4]
    __shared__ __align__(16) float Qs[64 * 36];        // [n 64][k 32 +4]
    __shared__ __align__(16) float red4[4 * 64 * 36];  // [wave][d 64][k 32 +4]
    __shared__ float mred[8][33];

    const int tid = threadIdx.x;
    const int bid = blockIdx.x;
    const int ns = bid & 31;
    const int dt = (bid >> 5) & 7;
    const int b  = bid >> 8;
    const int nsub = tid >> 5;
    const int dp = tid & 7;
    const int kp = (tid >> 3) & 3;
    const int k0t = kp << 3;           // contiguous 8-k slice
    const int wv = tid >> 6;

    v2f acc2[8][4];                    // [i over d][j2 over k-pairs]
#pragma unroll
    for (int i = 0; i < 8; ++i)
#pragma unroll
        for (int j = 0; j < 4; ++j) acc2[i][j] = (v2f)(0.f);

    const float* xsrc = X + ((size_t)b * D_DIM + dt * 64) * N_DIM + ns * 128;
    const float* qsrc = Qin + ((size_t)b * N_DIM + ns * 128) * K_DIM;

    for (int ch = 0; ch < 2; ++ch) {   // 2 chunks of 64 n
        __syncthreads();
#pragma unroll
        for (int i = 0; i < 4; ++i) {  // stage Xs: 64 d x 64 n
            int flat4 = tid + (i << 8);
            int row = flat4 >> 4;
            int c4  = (flat4 & 15) << 2;
            float4 v = *(const float4*)(xsrc + (size_t)row * N_DIM + (ch << 6) + c4);
            *(float4*)(&Xs[row * 68 + c4]) = v;
        }
#pragma unroll
        for (int i = 0; i < 2; ++i) {  // stage Qs [n][k]: direct, coalesced
            int flat4 = tid + (i << 8);
            int nn = flat4 >> 3;
            int k4 = (flat4 & 7) << 2;
            *(float4*)(&Qs[nn * 36 + k4]) =
                *(const float4*)(qsrc + ((ch << 6) + nn) * K_DIM + k4);
        }
        __syncthreads();
#pragma unroll
        for (int s = 0; s < 2; ++s) {
            const int nb = (nsub << 3) + (s << 2);
            float4 xr[8];
#pragma unroll
            for (int i = 0; i < 8; ++i)
                xr[i] = *(const float4*)(&Xs[(dp + (i << 3)) * 68 + nb]);
#pragma unroll
            for (int n = 0; n < 4; ++n) {
                float4 qa = *(const float4*)(&Qs[(nb + n) * 36 + k0t]);
                float4 qb = *(const float4*)(&Qs[(nb + n) * 36 + k0t + 4]);
                v2f q2[4] = {{qa.x, qa.y}, {qa.z, qa.w}, {qb.x, qb.y}, {qb.z, qb.w}};
#pragma unroll
                for (int i = 0; i < 8; ++i) {
                    v2f xlo = {xr[i].x, xr[i].y};
                    v2f xhi = {xr[i].z, xr[i].w};
                    v2f xb2 = (n < 2) ? xlo : xhi;
                    if ((n & 1) == 0) {
#pragma unroll
                        for (int j = 0; j < 4; ++j) pk_bl(acc2[i][j], q2[j], xb2);
                    } else {
#pragma unroll
                        for (int j = 0; j < 4; ++j) pk_bh(acc2[i][j], q2[j], xb2);
                    }
                }
            }
        }
    }
    // pair-reduce nsub (2w, 2w+1) via shfl, then per-wave slabs (no atomics)
    __syncthreads();
#pragma unroll
    for (int i = 0; i < 8; ++i)
#pragma unroll
        for (int j = 0; j < 4; ++j) {
            acc2[i][j].x += __shfl_xor(acc2[i][j].x, 32);
            acc2[i][j].y += __shfl_xor(acc2[i][j].y, 32);
        }
    if ((tid & 32) == 0) {
#pragma unroll
        for (int i = 0; i < 8; ++i) {
            float* r = &red4[(wv * 64 + dp + (i << 3)) * 36 + k0t];
            *(float4*)(r)     = make_float4(acc2[i][0].x, acc2[i][0].y,
                                            acc2[i][1].x, acc2[i][1].y);
            *(float4*)(r + 4) = make_float4(acc2[i][2].x, acc2[i][2].y,
                                            acc2[i][3].x, acc2[i][3].y);
        }
    }
    __syncthreads();
    // sum 4 wave slabs, store 64x32 tile (coalesced)
    float* dst = TP + (((size_t)ns * 2 + b) * D_DIM + dt * 64) * K_DIM;
#pragma unroll
    for (int e = 0; e < 8; ++e) {
        int flat = tid + (e << 8);          // 2048 cells
        int dl = flat >> 5;
        int k  = flat & 31;
        float s = red4[(0 * 64 + dl) * 36 + k] + red4[(1 * 64 + dl) * 36 + k]
                + red4[(2 * 64 + dl) * 36 + k] + red4[(3 * 64 + dl) * 36 + k];
        dst[dl * K_DIM + k] = s;
    }
    // dt==0 blocks: per-slab Q mass (L2-hot coalesced reads, no atomics)
    if (dt == 0) {
        const int k = tid & 31, g = tid >> 5;
        float qm = 0.f;
#pragma unroll
        for (int n = 0; n < 16; ++n)
            qm += qsrc[(g * 16 + n) * K_DIM + k];
        mred[g][k] = qm;
        __syncthreads();
        if (tid < K_DIM) {
            float t = 0.f;
#pragma unroll
            for (int i = 0; i < 8; ++i) t += mred[i][tid];
            Mpart[(ns * B_DIM + b) * K_DIM + tid] = t;
        }
    }
}

// ---------------------------------------------------------------------------
// K3 (fused zpre+zfin): sum 32 partials, M from Mpart, z = s*(T/M - c) held
// in registers; nsq via device-scope atomics; grid-wide completion via
// agent-scope counter (128 blocks <= 256 CUs -> co-residency guaranteed,
// no deadlock); then Z = z * rsqrt(nsq). No Ztmp buffer, no 4th dispatch.
// ---------------------------------------------------------------------------
__global__ __launch_bounds__(256)
void k_zfuse(const float* __restrict__ TP, const float* __restrict__ Mpart,
             const float* __restrict__ CW, const float* __restrict__ SC,
             float* __restrict__ Z, float* __restrict__ nsq, int* __restrict__ cnt)
{
    __shared__ float part[8][33];
    const int tid = threadIdx.x;
    const int b  = blockIdx.x >> 6;
    const int ds = blockIdx.x & 63;
    const int d  = (ds << 3) + (tid >> 5);
    const int k  = tid & 31;
    float sum = 0.f;
#pragma unroll
    for (int ns = 0; ns < 32; ++ns)
        sum += TP[(((size_t)ns * 2 + b) * D_DIM + d) * K_DIM + k];
    float m = 0.f;
#pragma unroll
    for (int ns = 0; ns < 32; ++ns)
        m += Mpart[(ns * B_DIM + b) * K_DIM + k];
    float c = CW[k * D_DIM + d];
    float s = SC[d * K_DIM + k];
    float z = s * (sum / m - c);
    part[tid >> 5][k] = z * z;
    __syncthreads();
    if (tid < K_DIM) {
        float t = 0.f;
#pragma unroll
        for (int i = 0; i < 8; ++i) t += part[i][tid];
        atomicAdd(&nsq[b * K_DIM + tid], t);
    }
    __syncthreads();   // barrier drains this block's atomics (vmcnt(0))
    if (tid == 0) {
        __hip_atomic_fetch_add(cnt, 1, __ATOMIC_ACQ_REL, __HIP_MEMORY_SCOPE_AGENT);
        while (__hip_atomic_load(cnt, __ATOMIC_ACQUIRE, __HIP_MEMORY_SCOPE_AGENT) < 128)
            __builtin_amdgcn_s_sleep(1);
    }
    __syncthreads();
    float nv = __hip_atomic_load(&nsq[b * K_DIM + k], __ATOMIC_RELAXED,
                                 __HIP_MEMORY_SCOPE_AGENT);
    Z[((b * D_DIM) + d) * K_DIM + k] = z * rsqrtf(nv);
}

extern "C" void kernel_launch(void* const* d_in, const int* in_sizes, int n_in,
                              void* d_out, int out_size, void* d_ws, size_t ws_size,
                              hipStream_t stream)
{
    const float* X  = (const float*)d_in[0];   // [2,512,64,64]
    const float* CW = (const float*)d_in[1];   // [32,512]
    const float* SC = (const float*)d_in[2];   // [512,32]
    float* Z = (float*)d_out;                              // [2,512,32]
    float* Q = (float*)d_out + B_DIM * D_DIM * K_DIM;      // [2,4096,32]

    float* W    = (float*)d_ws;
    float* nsq  = W;                                       // 64 floats
    int*   cnt  = (int*)(W + 64);                          // 1 int
    float* Mpart= W + 128;                                 // 32*2*32 = 2048
    float* TP   = W + 128 + 2048;                          // 4 MB

    k_dist_q<<<512, 256, 0, stream>>>(X, CW, SC, Q, nsq, cnt);
    k_tpart <<<512, 256, 0, stream>>>(X, Q, TP, Mpart);
    k_zfuse <<<128, 256, 0, stream>>>(TP, Mpart, CW, SC, Z, nsq, cnt);
}